// Round 15
// baseline (179.866 us; speedup 1.0000x reference)
//
#include <hip/hip_runtime.h>

typedef __attribute__((ext_vector_type(8))) short bf8;
typedef __attribute__((ext_vector_type(4))) float f32x4;
typedef __attribute__((ext_vector_type(16))) float f32x16;

static __device__ __forceinline__ unsigned short f2b(float x) {
    unsigned u = __builtin_bit_cast(unsigned, x);
    u += 0x7fffu + ((u >> 16) & 1u);
    return (unsigned short)(u >> 16);
}

static __device__ __forceinline__ void gload_lds16(const void* g, void* l) {
    __builtin_amdgcn_global_load_lds(
        (const __attribute__((address_space(1))) unsigned int*)g,
        (__attribute__((address_space(3))) unsigned int*)l, 16, 0, 0);
}

// ---------------- merged prep: XT transpose-cast + weight casts/reorder + BN fold + SUMK zero ----------
__global__ __launch_bounds__(256) void k_prep(
    const float* __restrict__ Wq, const float* __restrict__ Wk1, const float* __restrict__ Wv1,
    const float* __restrict__ Wk2, const float* __restrict__ Wv2, const float* __restrict__ Wc,
    const float* __restrict__ gamma, const float* __restrict__ beta,
    const float* __restrict__ rmean, const float* __restrict__ rvar,
    const float* __restrict__ F1, const float* __restrict__ F2,
    unsigned short* __restrict__ WQB, unsigned short* __restrict__ WKB, unsigned short* __restrict__ WVB,
    unsigned short* __restrict__ WCB, float* __restrict__ BNS, float* __restrict__ BNB,
    float* __restrict__ SUMK, unsigned short* __restrict__ XT)
{
    const int bid = blockIdx.x;
    if (bid < 4096) {
        __shared__ float tile[64][65];
        const int b = bid >> 9;
        const int c0 = ((bid >> 6) & 7) * 64;
        const int p0 = (bid & 63) * 64;
        const int tx = threadIdx.x & 63;
        const int ty = threadIdx.x >> 6;
        const float* src = (c0 < 256) ? F1 : F2;
        const int cb = c0 & 255;
#pragma unroll
        for (int i = 0; i < 16; i++) {
            int cl = i * 4 + ty;
            tile[cl][tx] = src[((size_t)b * 256 + cb + cl) * 4096 + p0 + tx];
        }
        __syncthreads();
        const int t = threadIdx.x;
        const int p = t >> 2;
        const int cg = (t & 3) * 16;
        unsigned short tmp[16];
#pragma unroll
        for (int j = 0; j < 16; j++) tmp[j] = f2b(tile[cg + j][p]);
        unsigned short* dst = XT + ((size_t)b * 4096 + p0 + p) * 512 + c0 + cg;
        *(uint4*)dst = *(const uint4*)tmp;
        *(uint4*)(dst + 8) = *(const uint4*)(tmp + 8);
        return;
    }
    const int total = 131072 + 4 * 65536 + 1179648 + 256 + 4096;
    for (int i = (bid - 4096) * 256 + threadIdx.x; i < total; i += 256 * 256) {
        int j = i;
        if (j < 131072) { WQB[j] = f2b(Wq[j]); continue; }
        j -= 131072;
        if (j < 65536) { WKB[j] = f2b(Wk1[j]); continue; }
        j -= 65536;
        if (j < 65536) { WKB[65536 + j] = f2b(Wk2[j]); continue; }
        j -= 65536;
        if (j < 65536) { WVB[j] = f2b(Wv1[j]); continue; }
        j -= 65536;
        if (j < 65536) { WVB[65536 + j] = f2b(Wv2[j]); continue; }
        j -= 65536;
        if (j < 1179648) {
            int cl = j & 63;
            int rest = j >> 6;
            int o = rest & 255;
            int tc = rest >> 8;
            int tap = tc >> 3, ccb = tc & 7;
            int c = ccb * 64 + cl;
            WCB[j] = f2b(Wc[(size_t)(o * 512 + c) * 9 + tap]);
            continue;
        }
        j -= 1179648;
        if (j < 256) {
            float inv = gamma[j] * rsqrtf(rvar[j] + 1e-5f);
            BNS[j] = inv;
            BNB[j] = beta[j] - rmean[j] * inv;
            continue;
        }
        j -= 256;
        SUMK[j] = 0.0f;
    }
}

// ---------------- 1x1 conv GEMM, LDS-staged ----------------
// MODE 2: softmax over head dim -> QS (outU). grid (32,2,8).
// MODE 3: exp(K) -> LDS; rowsums -> outF(SUMK); att-partial MFMA -> ATTP. grid (32,2,16), br=z>>3.
// MODE 4: V -> LDS; per-wave PV vs ATT (QSp); residual from resident LDS B-tiles -> outU(FUSED2).
template<int MODE>
__global__ __launch_bounds__(256) void k_gemm1x1(
    const unsigned short* __restrict__ A,
    const unsigned short* __restrict__ XT,
    const float* __restrict__ bias,
    const float* __restrict__ bias2,
    unsigned short* __restrict__ outU,
    float* __restrict__ outF,
    const unsigned short* __restrict__ QSp,
    float* __restrict__ ATTP,
    int Kd)
{
    __shared__ unsigned short lds[2][2][128 * 64]; // 64 KiB
    int br = 0, b = blockIdx.z, myy = blockIdx.y;
    if (MODE == 3) { br = blockIdx.z >> 3; b = blockIdx.z & 7; }
    if (MODE == 4) { br = blockIdx.y >> 1; myy = blockIdx.y & 1; }
    const int m0 = myy * 128;
    const int n0 = blockIdx.x * 128;
    const int co = (MODE == 2) ? 0 : br * 256;
    const unsigned short* Ab = A + (size_t)br * 65536;
    const float* bi = br ? bias2 : bias;
    const int lane = threadIdx.x & 63;
    const int wv = threadIdx.x >> 6;
    const int wr = wv >> 1, wc = wv & 1;
    const int lrow = lane & 15, kg = lane >> 4;
    const int px = lane >> 3, sl = lane & 7;
    const int nt = Kd >> 6;
    const int kts = (MODE == 4) ? (((m0 >> 6) + 2) & 3) : 0;

    f32x4 acc[4][4];
#pragma unroll
    for (int mi = 0; mi < 4; mi++)
#pragma unroll
        for (int ni = 0; ni < 4; ni++)
            acc[mi][ni] = (f32x4){0.f, 0.f, 0.f, 0.f};

    {
        int k0p = kts << 6;
#pragma unroll
        for (int j = 0; j < 4; j++) {
            int r0 = wv * 32 + j * 8;
            gload_lds16(Ab + (size_t)(m0 + r0 + px) * Kd + k0p + (sl ^ px) * 8, &lds[0][0][r0 * 64]);
            gload_lds16(XT + ((size_t)b * 4096 + n0 + r0 + px) * 512 + co + k0p + (sl ^ px) * 8, &lds[0][1][r0 * 64]);
        }
    }
    __syncthreads();

    int cb = 0;
    for (int kt = 0; kt < nt; kt++) {
        if (kt + 1 < nt) {
            int k0 = (MODE == 4) ? (((kts + kt + 1) & 3) << 6) : ((kt + 1) << 6);
            int nb = cb ^ 1;
#pragma unroll
            for (int j = 0; j < 4; j++) {
                int r0 = wv * 32 + j * 8;
                gload_lds16(Ab + (size_t)(m0 + r0 + px) * Kd + k0 + (sl ^ px) * 8, &lds[nb][0][r0 * 64]);
                gload_lds16(XT + ((size_t)b * 4096 + n0 + r0 + px) * 512 + co + k0 + (sl ^ px) * 8, &lds[nb][1][r0 * 64]);
            }
        }
        const unsigned short* wa = lds[cb][0];
        const unsigned short* wb = lds[cb][1];
#pragma unroll
        for (int klo = 0; klo < 64; klo += 32) {
            const int slin = klo >> 3;
            bf8 a[4], bv[4];
#pragma unroll
            for (int mi = 0; mi < 4; mi++) {
                int ol = wr * 64 + mi * 16 + lrow;
                a[mi] = *(const bf8*)(wa + ol * 64 + (((slin + kg) ^ (ol & 7)) * 8));
            }
#pragma unroll
            for (int ni = 0; ni < 4; ni++) {
                int nl = wc * 64 + ni * 16 + lrow;
                bv[ni] = *(const bf8*)(wb + nl * 64 + (((slin + kg) ^ (nl & 7)) * 8));
            }
#pragma unroll
            for (int mi = 0; mi < 4; mi++)
#pragma unroll
                for (int ni = 0; ni < 4; ni++)
                    acc[mi][ni] = __builtin_amdgcn_mfma_f32_16x16x32_bf16(a[mi], bv[ni], acc[mi][ni], 0, 0, 0);
        }
        __syncthreads();
        cb ^= 1;
    }

    if (MODE == 2) {
#pragma unroll
        for (int hh = 0; hh < 2; hh++) {
            float vv[2][4][4];
            float mx[4];
#pragma unroll
            for (int ni = 0; ni < 4; ni++) mx[ni] = -1e30f;
#pragma unroll
            for (int ms = 0; ms < 2; ms++) {
                int mi = hh * 2 + ms;
                int row0 = m0 + wr * 64 + mi * 16 + kg * 4;
#pragma unroll
                for (int r = 0; r < 4; r++) {
                    float bb = bi[row0 + r];
#pragma unroll
                    for (int ni = 0; ni < 4; ni++) {
                        float x = acc[mi][ni][r] + bb;
                        vv[ms][r][ni] = x;
                        mx[ni] = fmaxf(mx[ni], x);
                    }
                }
            }
#pragma unroll
            for (int ni = 0; ni < 4; ni++) {
                mx[ni] = fmaxf(mx[ni], __shfl_xor(mx[ni], 16, 64));
                mx[ni] = fmaxf(mx[ni], __shfl_xor(mx[ni], 32, 64));
            }
            float sm[4] = {0.f, 0.f, 0.f, 0.f};
#pragma unroll
            for (int ms = 0; ms < 2; ms++)
#pragma unroll
                for (int r = 0; r < 4; r++)
#pragma unroll
                    for (int ni = 0; ni < 4; ni++) {
                        float e = __expf(vv[ms][r][ni] - mx[ni]);
                        vv[ms][r][ni] = e;
                        sm[ni] += e;
                    }
#pragma unroll
            for (int ni = 0; ni < 4; ni++) {
                sm[ni] += __shfl_xor(sm[ni], 16, 64);
                sm[ni] += __shfl_xor(sm[ni], 32, 64);
                sm[ni] = 1.0f / sm[ni];
            }
            int h = (m0 + wr * 64 + hh * 32) >> 5;
#pragma unroll
            for (int ms = 0; ms < 2; ms++) {
                int e0 = ms * 16 + kg * 4;
#pragma unroll
                for (int r = 0; r < 4; r++)
#pragma unroll
                    for (int ni = 0; ni < 4; ni++) {
                        int col = n0 + wc * 64 + ni * 16 + lrow;
                        outU[((size_t)(b * 8 + h) * 32 + e0 + r) * 4096 + col] = f2b(vv[ms][r][ni] * sm[ni]);
                    }
            }
        }
    } else if (MODE == 3) {
        unsigned short* P = &lds[0][0][0];
        float* red = (float*)&lds[1][0][0];
        float ps[4][4];
#pragma unroll
        for (int mi = 0; mi < 4; mi++) {
            int rowl0 = wr * 64 + mi * 16 + kg * 4;
#pragma unroll
            for (int r = 0; r < 4; r++) {
                float bb = bi[m0 + rowl0 + r];
                int row = rowl0 + r;
                float s = 0.f;
#pragma unroll
                for (int ni = 0; ni < 4; ni++) {
                    float e = __expf(acc[mi][ni][r] + bb);
                    int col = wc * 64 + ni * 16 + lrow;
                    int slot = (col >> 3) ^ (row & 7);
                    P[row * 128 + slot * 8 + (col & 7)] = f2b(e);
                    s += e;
                }
                ps[mi][r] = s;
            }
        }
#pragma unroll
        for (int mi = 0; mi < 4; mi++)
#pragma unroll
            for (int r = 0; r < 4; r++)
                red[(wr * 64 + mi * 16 + kg * 4 + r) * 33 + wc * 16 + lrow] = ps[mi][r];
        __syncthreads();
        if (threadIdx.x < 128) {
            float s = 0.f;
#pragma unroll
            for (int j = 0; j < 32; j++) s += red[threadIdx.x * 33 + j];
            atomicAdd(&outF[br * 2048 + b * 256 + m0 + threadIdx.x], s);
        }
        const int hh = wv;
        const int bh = b * 8 + (m0 >> 5) + hh;
        const unsigned short* QSb = QSp + ((size_t)bh * 32) * 4096 + n0;
        f32x4 acc2[2][2];
#pragma unroll
        for (int mi2 = 0; mi2 < 2; mi2++)
#pragma unroll
            for (int ni2 = 0; ni2 < 2; ni2++)
                acc2[mi2][ni2] = (f32x4){0.f, 0.f, 0.f, 0.f};
#pragma unroll
        for (int ks = 0; ks < 4; ks++) {
            bf8 pa[2], qb[2];
#pragma unroll
            for (int mi2 = 0; mi2 < 2; mi2++) {
                int row = hh * 32 + mi2 * 16 + lrow;
                int slot = (ks * 4 + kg) ^ (row & 7);
                pa[mi2] = *(const bf8*)(P + row * 128 + slot * 8);
            }
#pragma unroll
            for (int ni2 = 0; ni2 < 2; ni2++)
                qb[ni2] = *(const bf8*)(QSb + (size_t)(ni2 * 16 + lrow) * 4096 + ks * 32 + kg * 8);
#pragma unroll
            for (int mi2 = 0; mi2 < 2; mi2++)
#pragma unroll
                for (int ni2 = 0; ni2 < 2; ni2++)
                    acc2[mi2][ni2] = __builtin_amdgcn_mfma_f32_16x16x32_bf16(pa[mi2], qb[ni2], acc2[mi2][ni2], 0, 0, 0);
        }
        float* dst = ATTP + (size_t)br * 2097152 + ((size_t)bh * 32 + (n0 >> 7)) * 1024;
#pragma unroll
        for (int mi2 = 0; mi2 < 2; mi2++)
#pragma unroll
            for (int ni2 = 0; ni2 < 2; ni2++)
#pragma unroll
                for (int r = 0; r < 4; r++)
                    dst[(mi2 * 16 + kg * 4 + r) * 32 + ni2 * 16 + lrow] = acc2[mi2][ni2][r];
    } else {
        // MODE 4: V tile -> swizzled vlds in the dead A-halves; residual from resident B-tiles.
        unsigned short* L = &lds[0][0][0];
#pragma unroll
        for (int mi = 0; mi < 4; mi++) {
#pragma unroll
            for (int ni = 0; ni < 4; ni++) {
                int ch0 = wr * 64 + mi * 16 + kg * 4;
                int p = wc * 64 + ni * 16 + lrow;
                int sg = ch0 >> 3;
                unsigned long long pk = 0;
#pragma unroll
                for (int r = 0; r < 4; r++) {
                    unsigned short us = f2b(acc[mi][ni][r] + bi[m0 + ch0 + r]);
                    pk |= (unsigned long long)us << (16 * r);
                }
                *(unsigned long long*)(L + wc * 16384 + (p & 63) * 128 + ((sg ^ (p & 15)) * 8) + (ch0 & 7)) = pk;
            }
        }
        __syncthreads();
        const int hl = wv;
        const int bh = b * 8 + (m0 >> 5) + hl;
        const unsigned short* ATTh = QSp + (size_t)br * 65536 + (size_t)bh * 1024;
        bf8 af[2];
#pragma unroll
        for (int mi2 = 0; mi2 < 2; mi2++)
            af[mi2] = *(const bf8*)(ATTh + (mi2 * 16 + lrow) * 32 + kg * 8);
#pragma unroll
        for (int ni2 = 0; ni2 < 8; ni2++) {
            int pp = ni2 * 16 + lrow;
            const bf8 bf = *(const bf8*)(L + (ni2 >> 2) * 16384 + (pp & 63) * 128 + (((hl * 4 + kg) ^ (pp & 15)) * 8));
            f32x4 pa0 = (f32x4){0.f, 0.f, 0.f, 0.f};
            f32x4 pa1 = (f32x4){0.f, 0.f, 0.f, 0.f};
            pa0 = __builtin_amdgcn_mfma_f32_16x16x32_bf16(af[0], bf, pa0, 0, 0, 0);
            pa1 = __builtin_amdgcn_mfma_f32_16x16x32_bf16(af[1], bf, pa1, 0, 0, 0);
#pragma unroll
            for (int mi2 = 0; mi2 < 2; mi2++) {
                f32x4 pa = mi2 ? pa1 : pa0;
                int cl = hl * 32 + mi2 * 16 + kg * 4;
                int buf = cl >> 6;
                int jj = cl & 63;
                int slot = (jj >> 3) ^ (pp & 7);
                unsigned long long rin = *(const unsigned long long*)
                    (L + buf * 16384 + 8192 + pp * 64 + slot * 8 + (jj & 7));
                int c0 = co + m0 + cl;
                size_t base = ((size_t)b * 4096 + n0 + pp) * 512 + c0;
                unsigned long long pk = 0;
#pragma unroll
                for (int r = 0; r < 4; r++) {
                    unsigned short us = (unsigned short)(rin >> (16 * r));
                    float f = __builtin_bit_cast(float, ((unsigned)us) << 16);
                    pk |= (unsigned long long)f2b(pa[r] + f) << (16 * r);
                }
                *(unsigned long long*)(outU + base) = pk;
            }
        }
    }
}

// ATT[d][e] = f2b( mu * sum_nch ATTP / SUMK[d] ), both branches (grid 128), float4 reads
__global__ __launch_bounds__(256) void k_att_red(const float* __restrict__ ATTP,
                                                 const float* __restrict__ SUMK,
                                                 const float* __restrict__ mup,
                                                 unsigned short* __restrict__ ATT)
{
    const int gid = blockIdx.x;
    const int br = gid >> 6, bh = gid & 63;
    const int b = bh >> 3, h = bh & 7;
    const int tid = threadIdx.x;
    const float mu = mup[0];
    const float* src = ATTP + (size_t)br * 2097152 + (size_t)bh * 32768;
    const int idx = tid * 4;
    const int d = idx >> 5;
    float4 s = {0.f, 0.f, 0.f, 0.f};
    for (int nch = 0; nch < 32; nch++) {
        float4 v = *(const float4*)&src[nch * 1024 + idx];
        s.x += v.x; s.y += v.y; s.z += v.z; s.w += v.w;
    }
    float inv = mu / SUMK[br * 2048 + b * 256 + h * 32 + d];
    unsigned long long pk = (unsigned long long)f2b(s.x * inv)
        | ((unsigned long long)f2b(s.y * inv) << 16)
        | ((unsigned long long)f2b(s.z * inv) << 32)
        | ((unsigned long long)f2b(s.w * inv) << 48);
    *(unsigned long long*)(ATT + (size_t)br * 65536 + (size_t)bh * 1024 + idx) = pk;
}

// ---------------- 3x3 conv: LDS-staged implicit GEMM + BN + ReLU (32x32x16 MFMA) ----------
__global__ __launch_bounds__(256) void k_conv3(
    const unsigned short* __restrict__ WB2,
    const unsigned short* __restrict__ FUSED,
    const float* __restrict__ BNS, const float* __restrict__ BNB,
    float* __restrict__ out)
{
    __shared__ unsigned short lds_in[4 * 72 * 64];
    __shared__ unsigned short lds_w[2][128 * 64];

    const int b = blockIdx.z;
    const int m0 = blockIdx.y * 128;
    const int ry = blockIdx.x;
    const int lane = threadIdx.x & 63;
    const int wv = threadIdx.x >> 6;
    const int wr = wv >> 1, wc = wv & 1;
    const int l31 = lane & 31, kh = lane >> 5;
    const int px = lane >> 3, sl = lane & 7;

    f32x16 acc[2][2];
#pragma unroll
    for (int mi = 0; mi < 2; mi++)
#pragma unroll
        for (int ni = 0; ni < 2; ni++)
#pragma unroll
            for (int r = 0; r < 16; r++)
                acc[mi][ni][r] = 0.f;

    for (int ccb = 0; ccb < 8; ccb++) {
        for (int u = wv; u < 36; u += 4) {
            int rl = u / 9, seg = u - rl * 9;
            int gy = ry * 2 + rl - 1;
            bool rowok = ((unsigned)gy < 64u);
            int xi0 = seg * 8;
            unsigned short* ldsb = lds_in + (rl * 72 + xi0) * 64;
            int x = xi0 + px - 4;
            const unsigned short* src = FUSED
                + ((size_t)(b * 4096 + gy * 64 + x)) * 512 + ccb * 64 + (sl ^ px) * 8;
            if (rowok && seg >= 1 && seg <= 7) {
                gload_lds16(src, ldsb);
            } else {
                uint4 v = {0u, 0u, 0u, 0u};
                if (rowok && ((unsigned)x < 64u)) v = *(const uint4*)src;
                *(uint4*)(ldsb + lane * 8) = v;
            }
        }
        {
            const unsigned short* base = WB2 + (((size_t)(0 * 8 + ccb) * 256) + m0) * 64;
#pragma unroll
            for (int jw = 0; jw < 4; jw++) {
                int o0 = wv * 32 + jw * 8;
                gload_lds16(base + (size_t)(o0 + px) * 64 + (sl ^ px) * 8, &lds_w[0][o0 * 64]);
            }
        }
        __syncthreads();

        for (int tap = 0; tap < 9; tap++) {
            if (tap < 8) {
                const unsigned short* base = WB2 + (((size_t)((tap + 1) * 8 + ccb) * 256) + m0) * 64;
                unsigned short* wdst = lds_w[(tap + 1) & 1];
#pragma unroll
                for (int jw = 0; jw < 4; jw++) {
                    int o0 = wv * 32 + jw * 8;
                    gload_lds16(base + (size_t)(o0 + px) * 64 + (sl ^ px) * 8, &wdst[o0 * 64]);
                }
            }
            const unsigned short* wb = lds_w[tap & 1];
            const int ky = tap / 3, kx = tap - ky * 3;
            const int rl = wc + ky;
#pragma unroll
            for (int ks = 0; ks < 4; ks++) {
                const int slotb = ks * 2 + kh;   // k-slot of 8 ch: slice ks covers slots {2ks, 2ks+1}
                bf8 a[2], bv[2];
#pragma unroll
                for (int mi = 0; mi < 2; mi++) {
                    int ol = wr * 64 + mi * 32 + l31;
                    a[mi] = *(const bf8*)(wb + ol * 64 + ((slotb ^ (ol & 7)) * 8));
                }
#pragma unroll
                for (int ni = 0; ni < 2; ni++) {
                    int xi = ni * 32 + l31 + kx + 3;
                    bv[ni] = *(const bf8*)(lds_in + (rl * 72 + xi) * 64 + ((slotb ^ (xi & 7)) * 8));
                }
#pragma unroll
                for (int mi = 0; mi < 2; mi++)
#pragma unroll
                    for (int ni = 0; ni < 2; ni++)
                        acc[mi][ni] = __builtin_amdgcn_mfma_f32_32x32x16_bf16(a[mi], bv[ni], acc[mi][ni], 0, 0, 0);
            }
            __syncthreads();
        }
    }

    // C/D mapping (m74/m101): col = lane&31, row = (reg&3) + 8*(reg>>2) + 4*(lane>>5)
#pragma unroll
    for (int mi = 0; mi < 2; mi++) {
#pragma unroll
        for (int ni = 0; ni < 2; ni++) {
            int p = (ry * 2 + wc) * 64 + ni * 32 + l31;
#pragma unroll
            for (int r = 0; r < 16; r++) {
                int o = m0 + wr * 64 + mi * 32 + (r & 3) + 8 * (r >> 2) + 4 * kh;
                float v = acc[mi][ni][r] * BNS[o] + BNB[o];
                out[((size_t)b * 256 + o) * 4096 + p] = fmaxf(v, 0.0f);
            }
        }
    }
}

// ---------------- host ----------------
extern "C" void kernel_launch(void* const* d_in, const int* in_sizes, int n_in,
                              void* d_out, int out_size, void* d_ws, size_t ws_size,
                              hipStream_t stream)
{
    (void)in_sizes; (void)n_in; (void)out_size; (void)ws_size;
    const float* F1 = (const float*)d_in[0];
    const float* F2 = (const float*)d_in[1];
    const float* Wq = (const float*)d_in[2];
    const float* bq = (const float*)d_in[3];
    const float* Wk1 = (const float*)d_in[4];
    const float* bk1 = (const float*)d_in[5];
    const float* Wv1 = (const float*)d_in[6];
    const float* bv1 = (const float*)d_in[7];
    const float* Wk2 = (const float*)d_in[8];
    const float* bk2 = (const float*)d_in[9];
    const float* Wv2 = (const float*)d_in[10];
    const float* bv2 = (const float*)d_in[11];
    const float* mu = (const float*)d_in[12];
    const float* Wc = (const float*)d_in[13];
    const float* gamma = (const float*)d_in[14];
    const float* beta = (const float*)d_in[15];
    const float* rmean = (const float*)d_in[16];
    const float* rvar = (const float*)d_in[17];

    char* ws = (char*)d_ws;
    size_t off = 0;
    auto give = [&](size_t bytes) -> char* {
        char* p = ws + off;
        off = (off + bytes + 255) & ~(size_t)255;
        return p;
    };
    unsigned short* XT     = (unsigned short*)give(33554432); // immutable after k_prep
    unsigned short* FUSED2 = (unsigned short*)give(33554432); // PV+residual output, conv3 input
    unsigned short* QS  = (unsigned short*)give(16777216);
    unsigned short* WQB = (unsigned short*)give(262144);
    unsigned short* WKB = (unsigned short*)give(262144);      // [K1|K2]
    unsigned short* WVB = (unsigned short*)give(262144);      // [V1|V2]
    unsigned short* WCB = (unsigned short*)give(2359296);
    unsigned short* ATT = (unsigned short*)give(262144);      // [br][64 bh][32][32] bf16
    float* BNS = (float*)give(1024);
    float* BNB = (float*)give(1024);
    float* ATTP = (float*)give(16777216);                     // [br][64 bh][32 nch][1024] fp32
    float* SUMK = (float*)give(16384);                        // [br][2048]

    // 1. prep (XT + weights + BN + SUMK zero)
    k_prep<<<4352, 256, 0, stream>>>(Wq, Wk1, Wv1, Wk2, Wv2, Wc, gamma, beta, rmean, rvar,
                                     F1, F2, WQB, WKB, WVB, WCB, BNS, BNB, SUMK, XT);
    // 2. fused query GEMM + softmax over d
    k_gemm1x1<2><<<dim3(32, 2, 8), 256, 0, stream>>>(WQB, XT, bq, nullptr, QS, nullptr, nullptr, nullptr, 512);
    // 3. both K-GEMMs (exp + rowsums + att-partials)
    k_gemm1x1<3><<<dim3(32, 2, 16), 256, 0, stream>>>(WKB, XT, bk1, bk2, nullptr, SUMK, QS, ATTP, 256);
    // 4. att reduce+scale, both branches
    k_att_red<<<128, 256, 0, stream>>>(ATTP, SUMK, mu, ATT);
    // 5. both V-GEMMs (+PV +residual from resident LDS)
    k_gemm1x1<4><<<dim3(32, 4, 8), 256, 0, stream>>>(WVB, XT, bv1, bv2, FUSED2, nullptr, ATT, nullptr, 256);
    // 6. 3x3 conv + BN + ReLU (32x32x16 MFMA)
    k_conv3<<<dim3(32, 2, 8), 256, 0, stream>>>(WCB, FUSED2, BNS, BNB, (float*)d_out);
}

// Round 16
// 171.137 us; speedup vs baseline: 1.0510x; 1.0510x over previous
//
#include <hip/hip_runtime.h>

typedef __attribute__((ext_vector_type(8))) short bf8;
typedef __attribute__((ext_vector_type(4))) float f32x4;

static __device__ __forceinline__ unsigned short f2b(float x) {
    unsigned u = __builtin_bit_cast(unsigned, x);
    u += 0x7fffu + ((u >> 16) & 1u);
    return (unsigned short)(u >> 16);
}

static __device__ __forceinline__ void gload_lds16(const void* g, void* l) {
    __builtin_amdgcn_global_load_lds(
        (const __attribute__((address_space(1))) unsigned int*)g,
        (__attribute__((address_space(3))) unsigned int*)l, 16, 0, 0);
}

// ---------------- merged prep: XT transpose-cast + weight casts/reorder + BN fold + SUMK zero ----------
__global__ __launch_bounds__(256) void k_prep(
    const float* __restrict__ Wq, const float* __restrict__ Wk1, const float* __restrict__ Wv1,
    const float* __restrict__ Wk2, const float* __restrict__ Wv2, const float* __restrict__ Wc,
    const float* __restrict__ gamma, const float* __restrict__ beta,
    const float* __restrict__ rmean, const float* __restrict__ rvar,
    const float* __restrict__ F1, const float* __restrict__ F2,
    unsigned short* __restrict__ WQB, unsigned short* __restrict__ WKB, unsigned short* __restrict__ WVB,
    unsigned short* __restrict__ WCB, float* __restrict__ BNS, float* __restrict__ BNB,
    float* __restrict__ SUMK, unsigned short* __restrict__ XT)
{
    const int bid = blockIdx.x;
    if (bid < 4096) {
        __shared__ float tile[64][65];
        const int b = bid >> 9;
        const int c0 = ((bid >> 6) & 7) * 64;
        const int p0 = (bid & 63) * 64;
        const int tx = threadIdx.x & 63;
        const int ty = threadIdx.x >> 6;
        const float* src = (c0 < 256) ? F1 : F2;
        const int cb = c0 & 255;
#pragma unroll
        for (int i = 0; i < 16; i++) {
            int cl = i * 4 + ty;
            tile[cl][tx] = src[((size_t)b * 256 + cb + cl) * 4096 + p0 + tx];
        }
        __syncthreads();
        const int t = threadIdx.x;
        const int p = t >> 2;
        const int cg = (t & 3) * 16;
        unsigned short tmp[16];
#pragma unroll
        for (int j = 0; j < 16; j++) tmp[j] = f2b(tile[cg + j][p]);
        unsigned short* dst = XT + ((size_t)b * 4096 + p0 + p) * 512 + c0 + cg;
        *(uint4*)dst = *(const uint4*)tmp;
        *(uint4*)(dst + 8) = *(const uint4*)(tmp + 8);
        return;
    }
    const int total = 131072 + 4 * 65536 + 1179648 + 256 + 4096;
    for (int i = (bid - 4096) * 256 + threadIdx.x; i < total; i += 256 * 256) {
        int j = i;
        if (j < 131072) { WQB[j] = f2b(Wq[j]); continue; }
        j -= 131072;
        if (j < 65536) { WKB[j] = f2b(Wk1[j]); continue; }
        j -= 65536;
        if (j < 65536) { WKB[65536 + j] = f2b(Wk2[j]); continue; }
        j -= 65536;
        if (j < 65536) { WVB[j] = f2b(Wv1[j]); continue; }
        j -= 65536;
        if (j < 65536) { WVB[65536 + j] = f2b(Wv2[j]); continue; }
        j -= 65536;
        if (j < 1179648) {
            int cl = j & 63;
            int rest = j >> 6;
            int o = rest & 255;
            int tc = rest >> 8;
            int tap = tc >> 3, ccb = tc & 7;
            int c = ccb * 64 + cl;
            WCB[j] = f2b(Wc[(size_t)(o * 512 + c) * 9 + tap]);
            continue;
        }
        j -= 1179648;
        if (j < 256) {
            float inv = gamma[j] * rsqrtf(rvar[j] + 1e-5f);
            BNS[j] = inv;
            BNB[j] = beta[j] - rmean[j] * inv;
            continue;
        }
        j -= 256;
        SUMK[j] = 0.0f;
    }
}

// ---------------- 1x1 conv GEMM, LDS-staged ----------------
// MODE 2: softmax over head dim -> QS (outU). grid (32,2,8).
// MODE 3: exp(K) -> LDS; rowsums -> outF(SUMK); att-partial MFMA -> ATTP. grid (32,2,16), br=z>>3.
// MODE 4: V -> LDS; per-wave PV vs ATT (QSp); residual from resident LDS B-tiles -> outU(FUSED2).
//         kt order permuted so the last two B-chunks are the residual channels. grid (32,4,8), br=y>>1.
template<int MODE>
__global__ __launch_bounds__(256) void k_gemm1x1(
    const unsigned short* __restrict__ A,
    const unsigned short* __restrict__ XT,
    const float* __restrict__ bias,
    const float* __restrict__ bias2,
    unsigned short* __restrict__ outU,
    float* __restrict__ outF,
    const unsigned short* __restrict__ QSp,
    float* __restrict__ ATTP,
    int Kd)
{
    __shared__ unsigned short lds[2][2][128 * 64]; // 64 KiB
    int br = 0, b = blockIdx.z, myy = blockIdx.y;
    if (MODE == 3) { br = blockIdx.z >> 3; b = blockIdx.z & 7; }
    if (MODE == 4) { br = blockIdx.y >> 1; myy = blockIdx.y & 1; }
    const int m0 = myy * 128;
    const int n0 = blockIdx.x * 128;
    const int co = (MODE == 2) ? 0 : br * 256;
    const unsigned short* Ab = A + (size_t)br * 65536;
    const float* bi = br ? bias2 : bias;
    const int lane = threadIdx.x & 63;
    const int wv = threadIdx.x >> 6;
    const int wr = wv >> 1, wc = wv & 1;
    const int lrow = lane & 15, kg = lane >> 4;
    const int px = lane >> 3, sl = lane & 7;
    const int nt = Kd >> 6;
    // MODE 4: permuted kt start so chunks (m0>>6) and (m0>>6)+1 land in lds[0]/lds[1] at the end
    const int kts = (MODE == 4) ? (((m0 >> 6) + 2) & 3) : 0;

    f32x4 acc[4][4];
#pragma unroll
    for (int mi = 0; mi < 4; mi++)
#pragma unroll
        for (int ni = 0; ni < 4; ni++)
            acc[mi][ni] = (f32x4){0.f, 0.f, 0.f, 0.f};

    {
        int k0p = kts << 6;
#pragma unroll
        for (int j = 0; j < 4; j++) {
            int r0 = wv * 32 + j * 8;
            gload_lds16(Ab + (size_t)(m0 + r0 + px) * Kd + k0p + (sl ^ px) * 8, &lds[0][0][r0 * 64]);
            gload_lds16(XT + ((size_t)b * 4096 + n0 + r0 + px) * 512 + co + k0p + (sl ^ px) * 8, &lds[0][1][r0 * 64]);
        }
    }
    __syncthreads();

    int cb = 0;
    for (int kt = 0; kt < nt; kt++) {
        if (kt + 1 < nt) {
            int k0 = (MODE == 4) ? (((kts + kt + 1) & 3) << 6) : ((kt + 1) << 6);
            int nb = cb ^ 1;
#pragma unroll
            for (int j = 0; j < 4; j++) {
                int r0 = wv * 32 + j * 8;
                gload_lds16(Ab + (size_t)(m0 + r0 + px) * Kd + k0 + (sl ^ px) * 8, &lds[nb][0][r0 * 64]);
                gload_lds16(XT + ((size_t)b * 4096 + n0 + r0 + px) * 512 + co + k0 + (sl ^ px) * 8, &lds[nb][1][r0 * 64]);
            }
        }
        const unsigned short* wa = lds[cb][0];
        const unsigned short* wb = lds[cb][1];
#pragma unroll
        for (int klo = 0; klo < 64; klo += 32) {
            const int slin = klo >> 3;
            bf8 a[4], bv[4];
#pragma unroll
            for (int mi = 0; mi < 4; mi++) {
                int ol = wr * 64 + mi * 16 + lrow;
                a[mi] = *(const bf8*)(wa + ol * 64 + (((slin + kg) ^ (ol & 7)) * 8));
            }
#pragma unroll
            for (int ni = 0; ni < 4; ni++) {
                int nl = wc * 64 + ni * 16 + lrow;
                bv[ni] = *(const bf8*)(wb + nl * 64 + (((slin + kg) ^ (nl & 7)) * 8));
            }
#pragma unroll
            for (int mi = 0; mi < 4; mi++)
#pragma unroll
                for (int ni = 0; ni < 4; ni++)
                    acc[mi][ni] = __builtin_amdgcn_mfma_f32_16x16x32_bf16(a[mi], bv[ni], acc[mi][ni], 0, 0, 0);
        }
        __syncthreads();
        cb ^= 1;
    }

    if (MODE == 2) {
#pragma unroll
        for (int hh = 0; hh < 2; hh++) {
            float vv[2][4][4];
            float mx[4];
#pragma unroll
            for (int ni = 0; ni < 4; ni++) mx[ni] = -1e30f;
#pragma unroll
            for (int ms = 0; ms < 2; ms++) {
                int mi = hh * 2 + ms;
                int row0 = m0 + wr * 64 + mi * 16 + kg * 4;
#pragma unroll
                for (int r = 0; r < 4; r++) {
                    float bb = bi[row0 + r];
#pragma unroll
                    for (int ni = 0; ni < 4; ni++) {
                        float x = acc[mi][ni][r] + bb;
                        vv[ms][r][ni] = x;
                        mx[ni] = fmaxf(mx[ni], x);
                    }
                }
            }
#pragma unroll
            for (int ni = 0; ni < 4; ni++) {
                mx[ni] = fmaxf(mx[ni], __shfl_xor(mx[ni], 16, 64));
                mx[ni] = fmaxf(mx[ni], __shfl_xor(mx[ni], 32, 64));
            }
            float sm[4] = {0.f, 0.f, 0.f, 0.f};
#pragma unroll
            for (int ms = 0; ms < 2; ms++)
#pragma unroll
                for (int r = 0; r < 4; r++)
#pragma unroll
                    for (int ni = 0; ni < 4; ni++) {
                        float e = __expf(vv[ms][r][ni] - mx[ni]);
                        vv[ms][r][ni] = e;
                        sm[ni] += e;
                    }
#pragma unroll
            for (int ni = 0; ni < 4; ni++) {
                sm[ni] += __shfl_xor(sm[ni], 16, 64);
                sm[ni] += __shfl_xor(sm[ni], 32, 64);
                sm[ni] = 1.0f / sm[ni];
            }
            int h = (m0 + wr * 64 + hh * 32) >> 5;
#pragma unroll
            for (int ms = 0; ms < 2; ms++) {
                int e0 = ms * 16 + kg * 4;
#pragma unroll
                for (int r = 0; r < 4; r++)
#pragma unroll
                    for (int ni = 0; ni < 4; ni++) {
                        int col = n0 + wc * 64 + ni * 16 + lrow;
                        outU[((size_t)(b * 8 + h) * 32 + e0 + r) * 4096 + col] = f2b(vv[ms][r][ni] * sm[ni]);
                    }
            }
        }
    } else if (MODE == 3) {
        unsigned short* P = &lds[0][0][0];
        float* red = (float*)&lds[1][0][0];
        float ps[4][4];
#pragma unroll
        for (int mi = 0; mi < 4; mi++) {
            int rowl0 = wr * 64 + mi * 16 + kg * 4;
#pragma unroll
            for (int r = 0; r < 4; r++) {
                float bb = bi[m0 + rowl0 + r];
                int row = rowl0 + r;
                float s = 0.f;
#pragma unroll
                for (int ni = 0; ni < 4; ni++) {
                    float e = __expf(acc[mi][ni][r] + bb);
                    int col = wc * 64 + ni * 16 + lrow;
                    int slot = (col >> 3) ^ (row & 7);
                    P[row * 128 + slot * 8 + (col & 7)] = f2b(e);
                    s += e;
                }
                ps[mi][r] = s;
            }
        }
#pragma unroll
        for (int mi = 0; mi < 4; mi++)
#pragma unroll
            for (int r = 0; r < 4; r++)
                red[(wr * 64 + mi * 16 + kg * 4 + r) * 33 + wc * 16 + lrow] = ps[mi][r];
        __syncthreads();
        if (threadIdx.x < 128) {
            float s = 0.f;
#pragma unroll
            for (int j = 0; j < 32; j++) s += red[threadIdx.x * 33 + j];
            atomicAdd(&outF[br * 2048 + b * 256 + m0 + threadIdx.x], s);
        }
        const int hh = wv;
        const int bh = b * 8 + (m0 >> 5) + hh;
        const unsigned short* QSb = QSp + ((size_t)bh * 32) * 4096 + n0;
        f32x4 acc2[2][2];
#pragma unroll
        for (int mi2 = 0; mi2 < 2; mi2++)
#pragma unroll
            for (int ni2 = 0; ni2 < 2; ni2++)
                acc2[mi2][ni2] = (f32x4){0.f, 0.f, 0.f, 0.f};
#pragma unroll
        for (int ks = 0; ks < 4; ks++) {
            bf8 pa[2], qb[2];
#pragma unroll
            for (int mi2 = 0; mi2 < 2; mi2++) {
                int row = hh * 32 + mi2 * 16 + lrow;
                int slot = (ks * 4 + kg) ^ (row & 7);
                pa[mi2] = *(const bf8*)(P + row * 128 + slot * 8);
            }
#pragma unroll
            for (int ni2 = 0; ni2 < 2; ni2++)
                qb[ni2] = *(const bf8*)(QSb + (size_t)(ni2 * 16 + lrow) * 4096 + ks * 32 + kg * 8);
#pragma unroll
            for (int mi2 = 0; mi2 < 2; mi2++)
#pragma unroll
                for (int ni2 = 0; ni2 < 2; ni2++)
                    acc2[mi2][ni2] = __builtin_amdgcn_mfma_f32_16x16x32_bf16(pa[mi2], qb[ni2], acc2[mi2][ni2], 0, 0, 0);
        }
        float* dst = ATTP + (size_t)br * 2097152 + ((size_t)bh * 32 + (n0 >> 7)) * 1024;
#pragma unroll
        for (int mi2 = 0; mi2 < 2; mi2++)
#pragma unroll
            for (int ni2 = 0; ni2 < 2; ni2++)
#pragma unroll
                for (int r = 0; r < 4; r++)
                    dst[(mi2 * 16 + kg * 4 + r) * 32 + ni2 * 16 + lrow] = acc2[mi2][ni2][r];
    } else {
        // MODE 4: V tile -> swizzled vlds in the dead A-halves (lds[buf][0]); B-halves keep the
        // residual XT chunks (kt-reordered so lds[buf][1] = channels m0 + buf*64 .. +63).
        unsigned short* L = &lds[0][0][0];
#pragma unroll
        for (int mi = 0; mi < 4; mi++) {
#pragma unroll
            for (int ni = 0; ni < 4; ni++) {
                int ch0 = wr * 64 + mi * 16 + kg * 4;
                int p = wc * 64 + ni * 16 + lrow;
                int sg = ch0 >> 3;
                unsigned long long pk = 0;
#pragma unroll
                for (int r = 0; r < 4; r++) {
                    unsigned short us = f2b(acc[mi][ni][r] + bi[m0 + ch0 + r]);
                    pk |= (unsigned long long)us << (16 * r);
                }
                *(unsigned long long*)(L + wc * 16384 + (p & 63) * 128 + ((sg ^ (p & 15)) * 8) + (ch0 & 7)) = pk;
            }
        }
        __syncthreads();
        const int hl = wv;
        const int bh = b * 8 + (m0 >> 5) + hl;
        const unsigned short* ATTh = QSp + (size_t)br * 65536 + (size_t)bh * 1024;
        bf8 af[2];
#pragma unroll
        for (int mi2 = 0; mi2 < 2; mi2++)
            af[mi2] = *(const bf8*)(ATTh + (mi2 * 16 + lrow) * 32 + kg * 8);
#pragma unroll
        for (int ni2 = 0; ni2 < 8; ni2++) {
            int pp = ni2 * 16 + lrow;
            const bf8 bf = *(const bf8*)(L + (ni2 >> 2) * 16384 + (pp & 63) * 128 + (((hl * 4 + kg) ^ (pp & 15)) * 8));
            f32x4 pa0 = (f32x4){0.f, 0.f, 0.f, 0.f};
            f32x4 pa1 = (f32x4){0.f, 0.f, 0.f, 0.f};
            pa0 = __builtin_amdgcn_mfma_f32_16x16x32_bf16(af[0], bf, pa0, 0, 0, 0);
            pa1 = __builtin_amdgcn_mfma_f32_16x16x32_bf16(af[1], bf, pa1, 0, 0, 0);
#pragma unroll
            for (int mi2 = 0; mi2 < 2; mi2++) {
                f32x4 pa = mi2 ? pa1 : pa0;
                int cl = hl * 32 + mi2 * 16 + kg * 4;          // local channel within [m0, m0+128)
                int buf = cl >> 6;                              // which B-tile holds it
                int jj = cl & 63;                               // col within chunk
                int slot = (jj >> 3) ^ (pp & 7);                // B-tile swizzle
                unsigned long long rin = *(const unsigned long long*)
                    (L + buf * 16384 + 8192 + pp * 64 + slot * 8 + (jj & 7));
                int c0 = co + m0 + cl;
                size_t base = ((size_t)b * 4096 + n0 + pp) * 512 + c0;
                unsigned long long pk = 0;
#pragma unroll
                for (int r = 0; r < 4; r++) {
                    unsigned short us = (unsigned short)(rin >> (16 * r));
                    float f = __builtin_bit_cast(float, ((unsigned)us) << 16);
                    pk |= (unsigned long long)f2b(pa[r] + f) << (16 * r);
                }
                *(unsigned long long*)(outU + base) = pk;
            }
        }
    }
}

// ATT[d][e] = f2b( mu * sum_nch ATTP / SUMK[d] ), both branches (grid 128), float4 reads
__global__ __launch_bounds__(256) void k_att_red(const float* __restrict__ ATTP,
                                                 const float* __restrict__ SUMK,
                                                 const float* __restrict__ mup,
                                                 unsigned short* __restrict__ ATT)
{
    const int gid = blockIdx.x;
    const int br = gid >> 6, bh = gid & 63;
    const int b = bh >> 3, h = bh & 7;
    const int tid = threadIdx.x;
    const float mu = mup[0];
    const float* src = ATTP + (size_t)br * 2097152 + (size_t)bh * 32768;
    const int idx = tid * 4;
    const int d = idx >> 5;
    float4 s = {0.f, 0.f, 0.f, 0.f};
    for (int nch = 0; nch < 32; nch++) {
        float4 v = *(const float4*)&src[nch * 1024 + idx];
        s.x += v.x; s.y += v.y; s.z += v.z; s.w += v.w;
    }
    float inv = mu / SUMK[br * 2048 + b * 256 + h * 32 + d];
    unsigned long long pk = (unsigned long long)f2b(s.x * inv)
        | ((unsigned long long)f2b(s.y * inv) << 16)
        | ((unsigned long long)f2b(s.z * inv) << 32)
        | ((unsigned long long)f2b(s.w * inv) << 48);
    *(unsigned long long*)(ATT + (size_t)br * 65536 + (size_t)bh * 1024 + idx) = pk;
}

// ---------------- 3x3 conv: LDS-staged implicit GEMM + BN + ReLU (pristine R9/R14 structure) ----------
__global__ __launch_bounds__(256) void k_conv3(
    const unsigned short* __restrict__ WB2,
    const unsigned short* __restrict__ FUSED,
    const float* __restrict__ BNS, const float* __restrict__ BNB,
    float* __restrict__ out)
{
    __shared__ unsigned short lds_in[4 * 72 * 64];
    __shared__ unsigned short lds_w[2][128 * 64];

    const int b = blockIdx.z;
    const int m0 = blockIdx.y * 128;
    const int ry = blockIdx.x;
    const int lane = threadIdx.x & 63;
    const int wv = threadIdx.x >> 6;
    const int wr = wv >> 1, wc = wv & 1;
    const int lrow = lane & 15, kg = lane >> 4;
    const int px = lane >> 3, sl = lane & 7;

    f32x4 acc[4][4];
#pragma unroll
    for (int mi = 0; mi < 4; mi++)
#pragma unroll
        for (int ni = 0; ni < 4; ni++)
            acc[mi][ni] = (f32x4){0.f, 0.f, 0.f, 0.f};

    for (int ccb = 0; ccb < 8; ccb++) {
        for (int u = wv; u < 36; u += 4) {
            int rl = u / 9, seg = u - rl * 9;
            int gy = ry * 2 + rl - 1;
            bool rowok = ((unsigned)gy < 64u);
            int xi0 = seg * 8;
            unsigned short* ldsb = lds_in + (rl * 72 + xi0) * 64;
            int x = xi0 + px - 4;
            const unsigned short* src = FUSED
                + ((size_t)(b * 4096 + gy * 64 + x)) * 512 + ccb * 64 + (sl ^ px) * 8;
            if (rowok && seg >= 1 && seg <= 7) {
                gload_lds16(src, ldsb);
            } else {
                uint4 v = {0u, 0u, 0u, 0u};
                if (rowok && ((unsigned)x < 64u)) v = *(const uint4*)src;
                *(uint4*)(ldsb + lane * 8) = v;
            }
        }
        {
            const unsigned short* base = WB2 + (((size_t)(0 * 8 + ccb) * 256) + m0) * 64;
#pragma unroll
            for (int jw = 0; jw < 4; jw++) {
                int o0 = wv * 32 + jw * 8;
                gload_lds16(base + (size_t)(o0 + px) * 64 + (sl ^ px) * 8, &lds_w[0][o0 * 64]);
            }
        }
        __syncthreads();

        for (int tap = 0; tap < 9; tap++) {
            if (tap < 8) {
                const unsigned short* base = WB2 + (((size_t)((tap + 1) * 8 + ccb) * 256) + m0) * 64;
                unsigned short* wdst = lds_w[(tap + 1) & 1];
#pragma unroll
                for (int jw = 0; jw < 4; jw++) {
                    int o0 = wv * 32 + jw * 8;
                    gload_lds16(base + (size_t)(o0 + px) * 64 + (sl ^ px) * 8, &wdst[o0 * 64]);
                }
            }
            const unsigned short* wb = lds_w[tap & 1];
            const int ky = tap / 3, kx = tap - ky * 3;
            const int rl = wc + ky;
#pragma unroll
            for (int k0 = 0; k0 < 64; k0 += 32) {
                const int slin = k0 >> 3;
                bf8 a[4], bv[4];
#pragma unroll
                for (int mi = 0; mi < 4; mi++) {
                    int ol = wr * 64 + mi * 16 + lrow;
                    int s = (slin + kg) ^ (ol & 7);
                    a[mi] = *(const bf8*)(wb + ol * 64 + s * 8);
                }
#pragma unroll
                for (int ni = 0; ni < 4; ni++) {
                    int xi = ni * 16 + lrow + kx + 3;
                    int s = (slin + kg) ^ (xi & 7);
                    bv[ni] = *(const bf8*)(lds_in + (rl * 72 + xi) * 64 + s * 8);
                }
#pragma unroll
                for (int mi = 0; mi < 4; mi++)
#pragma unroll
                    for (int ni = 0; ni < 4; ni++)
                        acc[mi][ni] = __builtin_amdgcn_mfma_f32_16x16x32_bf16(a[mi], bv[ni], acc[mi][ni], 0, 0, 0);
            }
            __syncthreads();
        }
    }

#pragma unroll
    for (int mi = 0; mi < 4; mi++) {
#pragma unroll
        for (int ni = 0; ni < 4; ni++) {
            int o0 = m0 + wr * 64 + mi * 16 + kg * 4;
            int p = (ry * 2 + wc) * 64 + ni * 16 + lrow;
#pragma unroll
            for (int r = 0; r < 4; r++) {
                int o = o0 + r;
                float v = acc[mi][ni][r] * BNS[o] + BNB[o];
                out[((size_t)b * 256 + o) * 4096 + p] = fmaxf(v, 0.0f);
            }
        }
    }
}

// ---------------- host ----------------
extern "C" void kernel_launch(void* const* d_in, const int* in_sizes, int n_in,
                              void* d_out, int out_size, void* d_ws, size_t ws_size,
                              hipStream_t stream)
{
    (void)in_sizes; (void)n_in; (void)out_size; (void)ws_size;
    const float* F1 = (const float*)d_in[0];
    const float* F2 = (const float*)d_in[1];
    const float* Wq = (const float*)d_in[2];
    const float* bq = (const float*)d_in[3];
    const float* Wk1 = (const float*)d_in[4];
    const float* bk1 = (const float*)d_in[5];
    const float* Wv1 = (const float*)d_in[6];
    const float* bv1 = (const float*)d_in[7];
    const float* Wk2 = (const float*)d_in[8];
    const float* bk2 = (const float*)d_in[9];
    const float* Wv2 = (const float*)d_in[10];
    const float* bv2 = (const float*)d_in[11];
    const float* mu = (const float*)d_in[12];
    const float* Wc = (const float*)d_in[13];
    const float* gamma = (const float*)d_in[14];
    const float* beta = (const float*)d_in[15];
    const float* rmean = (const float*)d_in[16];
    const float* rvar = (const float*)d_in[17];

    char* ws = (char*)d_ws;
    size_t off = 0;
    auto give = [&](size_t bytes) -> char* {
        char* p = ws + off;
        off = (off + bytes + 255) & ~(size_t)255;
        return p;
    };
    unsigned short* XT     = (unsigned short*)give(33554432); // immutable after k_prep
    unsigned short* FUSED2 = (unsigned short*)give(33554432); // PV+residual output, conv3 input
    unsigned short* QS  = (unsigned short*)give(16777216);
    unsigned short* WQB = (unsigned short*)give(262144);
    unsigned short* WKB = (unsigned short*)give(262144);      // [K1|K2]
    unsigned short* WVB = (unsigned short*)give(262144);      // [V1|V2]
    unsigned short* WCB = (unsigned short*)give(2359296);
    unsigned short* ATT = (unsigned short*)give(262144);      // [br][64 bh][32][32] bf16
    float* BNS = (float*)give(1024);
    float* BNB = (float*)give(1024);
    float* ATTP = (float*)give(16777216);                     // [br][64 bh][32 nch][1024] fp32
    float* SUMK = (float*)give(16384);                        // [br][2048]

    // 1. prep (XT + weights + BN + SUMK zero)
    k_prep<<<4352, 256, 0, stream>>>(Wq, Wk1, Wv1, Wk2, Wv2, Wc, gamma, beta, rmean, rvar,
                                     F1, F2, WQB, WKB, WVB, WCB, BNS, BNB, SUMK, XT);
    // 2. fused query GEMM + softmax over d
    k_gemm1x1<2><<<dim3(32, 2, 8), 256, 0, stream>>>(WQB, XT, bq, nullptr, QS, nullptr, nullptr, nullptr, 512);
    // 3. both K-GEMMs (exp + rowsums + att-partials)
    k_gemm1x1<3><<<dim3(32, 2, 16), 256, 0, stream>>>(WKB, XT, bk1, bk2, nullptr, SUMK, QS, ATTP, 256);
    // 4. att reduce+scale, both branches
    k_att_red<<<128, 256, 0, stream>>>(ATTP, SUMK, mu, ATT);
    // 5. both V-GEMMs (+PV +residual from resident LDS)
    k_gemm1x1<4><<<dim3(32, 4, 8), 256, 0, stream>>>(WVB, XT, bv1, bv2, FUSED2, nullptr, ATT, nullptr, 256);
    // 6. 3x3 conv + BN + ReLU
    k_conv3<<<dim3(32, 2, 8), 256, 0, stream>>>(WCB, FUSED2, BNS, BNB, (float*)d_out);
}